// Round 19
// baseline (27758.493 us; speedup 1.0000x reference)
//
#include <hip/hip_runtime.h>
#include <stdint.h>
#include <stddef.h>

#define B_  64
#define T_  2048
#define XD  256
#define H_  512
#define G4  2048          // 4*H
#define BT_ (B_*T_)       // 131072

typedef __attribute__((ext_vector_type(8))) _Float16 f16x8;
typedef __attribute__((ext_vector_type(4))) float f32x4;
typedef __attribute__((ext_vector_type(4))) unsigned int u32x4;
typedef __attribute__((ext_vector_type(4))) unsigned short us4;
typedef __attribute__((ext_vector_type(2))) _Float16 f16x2;

typedef __attribute__((address_space(3))) unsigned short lds_us;
typedef __attribute__((address_space(1))) const unsigned short gl_us;

// ---------------- static device scratch (total ~1.42 GB < 2 GiB PC32-reloc budget) ----
__device__ __attribute__((aligned(256))) unsigned short g_xh[(size_t)BT_*XD];         // x fp16
__device__ __attribute__((aligned(256))) unsigned short g_w1h[(size_t)2*G4*XD];       // w_ih_l0 fp16
__device__ __attribute__((aligned(256))) unsigned short g_w2h[(size_t)2*G4*1024];     // w_ih_l1 fp16
__device__ __attribute__((aligned(256))) _Float16       g_xproj[(size_t)2*BT_*G4];    // 1.07 GB fp16
__device__ __attribute__((aligned(256))) unsigned short g_out1[(size_t)BT_*1024];     // 268 MB fp16
__device__ __attribute__((aligned(256))) float          g_hlast[2][B_*H_];            // layer2 final h
// epoch-embedded h exchange, 3 rotating buffers (clobber-safe), granule =
// {cols01, epoch, cols23, epoch}: each 64b half atomic + self-validating.
// [layer][dir][buf3][seq][128 granules][4 dw]  (= 1.5 MB)
__device__ __attribute__((aligned(256))) unsigned int   g_hx[2][2][3][B_][128][4];

__device__ inline unsigned short f2h(float f) {
  _Float16 h = (_Float16)f;
  return __builtin_bit_cast(unsigned short, h);
}
__device__ inline float sigf(float x)  { return 1.f/(1.f + __expf(-x)); }
__device__ inline float tanh_(float x) { return 1.f - 2.f/(__expf(2.f*x) + 1.f); }

// ---------------- init: zero h-exchange buffers (epoch 0 valid for s=0) --------------
__global__ void k_init() {
  unsigned int i = blockIdx.x*256u + threadIdx.x;
  unsigned int stride = gridDim.x*256u;
  unsigned int* hx = (unsigned int*)&g_hx[0][0][0][0][0][0];
  for (unsigned int j = i; j < sizeof(g_hx)/4; j += stride) hx[j] = 0u;
}

// ---------------- fp32 -> fp16 converts ----------------
__global__ void k_cvt_x(const float* __restrict__ src) {
  const size_t n4 = (size_t)BT_*XD/4;
  for (size_t j = (size_t)blockIdx.x*blockDim.x + threadIdx.x; j < n4;
       j += (size_t)gridDim.x*blockDim.x) {
    float4 v = ((const float4*)src)[j];
    us4 o = { f2h(v.x), f2h(v.y), f2h(v.z), f2h(v.w) };
    ((us4*)g_xh)[j] = o;
  }
}
__global__ void k_cvt_w1(const float* __restrict__ src) {
  const size_t n4 = (size_t)2*G4*XD/4;
  for (size_t j = (size_t)blockIdx.x*blockDim.x + threadIdx.x; j < n4;
       j += (size_t)gridDim.x*blockDim.x) {
    float4 v = ((const float4*)src)[j];
    us4 o = { f2h(v.x), f2h(v.y), f2h(v.z), f2h(v.w) };
    ((us4*)g_w1h)[j] = o;
  }
}
__global__ void k_cvt_w2(const float* __restrict__ src) {
  const size_t n4 = (size_t)2*G4*1024/4;
  for (size_t j = (size_t)blockIdx.x*blockDim.x + threadIdx.x; j < n4;
       j += (size_t)gridDim.x*blockDim.x) {
    float4 v = ((const float4*)src)[j];
    us4 o = { f2h(v.x), f2h(v.y), f2h(v.z), f2h(v.w) };
    ((us4*)g_w2h)[j] = o;
  }
}

// ---------------- x_proj GEMM (r18: global_load_lds, linear LDS, XCD swizzle) -------
template<int LAYER>
__global__ __launch_bounds__(256) void k_xproj(const float* __restrict__ b_ih,
                                               const float* __restrict__ b_hh,
                                               const int* __restrict__ lens) {
  constexpr int K = (LAYER == 0) ? XD : 1024;
  const unsigned short* __restrict__ Abf = (LAYER == 0) ? g_xh : g_out1;
  const unsigned short* __restrict__ Wbf = (LAYER == 0) ? g_w1h : g_w2h;

  const int nmx = gridDim.x;
  const int bx  = (int)((blockIdx.x & 7)*(nmx >> 3) + (blockIdx.x >> 3));
  const int m0 = bx*128;
  const int n0 = blockIdx.y*128;
  const int d  = blockIdx.z;
  const int bseq = m0 / T_;
  const int t0   = m0 % T_;
  if (t0 >= lens[bseq]) return;

  __shared__ unsigned short As[128*64];
  __shared__ unsigned short Bs[128*64];

  const int tid  = threadIdx.x;
  const int lane = tid & 63;
  const int wv   = tid >> 6;
  const int moff = (wv >> 1)*64;
  const int noff = (wv & 1)*64;

  f32x4 acc[4][4] = {};

  const unsigned short* Ag = Abf + (size_t)m0*K;
  const unsigned short* Wg = Wbf + ((size_t)d*G4 + n0)*K;

  const int srow_l = lane >> 3;
  const int scol_l = (lane & 7)*8;

  for (int k0 = 0; k0 < K; k0 += 64) {
    __syncthreads();
    #pragma unroll
    for (int j = 0; j < 4; ++j) {
      const int inst = wv*4 + j;
      const int row  = inst*8 + srow_l;
      const unsigned short* ga = Ag + (size_t)row*K + k0 + scol_l;
      const unsigned short* gb = Wg + (size_t)row*K + k0 + scol_l;
      __builtin_amdgcn_global_load_lds((gl_us*)ga, (lds_us*)(As + inst*512), 16, 0, 0);
      __builtin_amdgcn_global_load_lds((gl_us*)gb, (lds_us*)(Bs + inst*512), 16, 0, 0);
    }
    __syncthreads();
    #pragma unroll
    for (int kt = 0; kt < 2; ++kt) {
      int slot = kt*4 + (lane >> 4);
      f16x8 af[4], bfv[4];
      #pragma unroll
      for (int mt = 0; mt < 4; ++mt) {
        int r = moff + mt*16 + (lane & 15);
        af[mt] = *(const f16x8*)(As + r*64 + slot*8);
      }
      #pragma unroll
      for (int nt = 0; nt < 4; ++nt) {
        int r = noff + nt*16 + (lane & 15);
        bfv[nt] = *(const f16x8*)(Bs + r*64 + slot*8);
      }
      #pragma unroll
      for (int mt = 0; mt < 4; ++mt)
        #pragma unroll
        for (int nt = 0; nt < 4; ++nt)
          acc[mt][nt] = __builtin_amdgcn_mfma_f32_16x16x32_f16(af[mt], bfv[nt], acc[mt][nt], 0, 0, 0);
    }
  }

  #pragma unroll
  for (int nt = 0; nt < 4; ++nt) {
    const int col = n0 + noff + nt*16 + (lane & 15);
    const float bias = b_ih[d*G4 + col] + b_hh[d*G4 + col];
    #pragma unroll
    for (int mt = 0; mt < 4; ++mt) {
      const int row = m0 + moff + mt*16 + (lane >> 4)*4;
      _Float16* op = g_xproj + ((size_t)d*BT_ + row)*G4 + col;
      #pragma unroll
      for (int j = 0; j < 4; ++j)
        op[(size_t)j*G4] = (_Float16)(acc[mt][nt][j] + bias);
    }
  }
}

// ---------------- recurrent scan: barrier-free, 3-buffer epoch granules -------------
// 128 blocks: dir=bid&1, wg=bid>>1. WG owns h-cols [wg*8,wg*8+8).
// Plane wv (seqs [16wv,16wv+16)) is uniform ACROSS WGs -> each wave self-syncs on
// the data: poll 32 granules of buf[s%3] until each 64b half shows epoch==s (rows
// with lenRow<=s accept anything: C row m depends only on A row m, output masked).
// Store granules (epoch s+1) to buf[(s+1)%3] with NO ack wait. No s_barrier, no
// flags. 3-buffer clobber proof: writer at step s overwrites epoch s-2 data; it
// reached s only because all plane waves stored epoch s-1, i.e. completed their
// epoch-(s-2) reads.
template<int LAYER>
__global__ __launch_bounds__(256, 1) void k_scan(const float* __restrict__ w_hh,
                                                 const int* __restrict__ lens) {
  const int dir  = blockIdx.x & 1;
  const int wg   = blockIdx.x >> 1;
  const int tid  = threadIdx.x;
  const int lane = tid & 63;
  const int wv   = tid >> 6;

  __shared__ unsigned short Wl[32*512];   // 32 KB, XOR-swizzled
  __shared__ float gs[64*33];             // gate scratch (wave-disjoint rows)

  for (int i = tid; i < 32*256; i += 256) {
    int e = i*2;
    int row = e >> 9;
    int k   = e & 511;
    int gate = row >> 3, hc = row & 7;
    int grow = gate*H_ + wg*8 + hc;
    const float* wsrc = w_hh + ((size_t)dir*G4 + grow)*H_ + k;
    unsigned int pk = (unsigned int)f2h(wsrc[0]) | ((unsigned int)f2h(wsrc[1]) << 16);
    int byte = row*1024 + ((((k*2) >> 4) ^ (row & 7)) << 4) + ((k*2) & 15);
    *(unsigned int*)((char*)Wl + byte) = pk;
  }
  __syncthreads();   // Wl read-only from here

  const int myseq = tid >> 2;                 // gate/writer role
  const int hcA   = (tid & 3)*2;
  const int mylen = lens[myseq];
  const int ml16  = __builtin_amdgcn_readfirstlane(lens[wv << 4]); // plane max len
  const int col0  = wg*8;
  const int arow  = wv*16 + (lane & 15);      // reader A-row (seq)
  const int lenA  = lens[arow];
  const int half  = lane >> 4;
  const int r0f   = lane & 15, r1f = 16 + (lane & 15);
  float c0 = 0.f, c1 = 0.f, h0k = 0.f, h1k = 0.f;
  unsigned int hold = 0u;

  const unsigned int* hxbase = &g_hx[LAYER][dir][0][0][0][0];  // block-uniform (SGPR)
  const unsigned int BUFB = 64*128*16;                          // 128 KB per buffer

  const unsigned int rd_base = (unsigned int)(arow*2048 + half*32);
  const unsigned int wr_base = (unsigned int)(myseq*2048 + (wg*2 + ((tid & 3) >> 1))*16);
  const bool is_writer = (tid & 1) == 0;

  const char* xbase = (const char*)((const unsigned int*)
      (g_xproj + (((size_t)dir*B_ + myseq)*T_)*G4 + col0) + (hcA >> 1));

  // prologue: prefetch xg for s=0
  unsigned int nx0, nx1, nx2, nx3;
  {
    int p0 = dir ? (mylen - 1) : 0;
    const char* xr = xbase + (size_t)p0*4096;
    asm volatile("global_load_dword %0, %1, off"             : "=v"(nx0) : "v"(xr) : "memory");
    asm volatile("global_load_dword %0, %1, off offset:1024" : "=v"(nx1) : "v"(xr) : "memory");
    asm volatile("global_load_dword %0, %1, off offset:2048" : "=v"(nx2) : "v"(xr) : "memory");
    asm volatile("global_load_dword %0, %1, off offset:3072" : "=v"(nx3) : "v"(xr) : "memory");
  }

  int rb = 0;                                  // s % 3
  for (int s = 0; s < ml16; ++s) {
    const int wb = (rb == 2) ? 0 : rb + 1;     // (s+1) % 3
    const unsigned int rd_voff = (unsigned int)rb*BUFB + rd_base;
    const unsigned int wr_voff = (unsigned int)wb*BUFB + wr_base;
    const bool act = s < mylen;
    const unsigned int tgt = (unsigned int)s;
    const bool staleok = (s >= lenA);          // finished row: output masked anyway

    // ---- 1. poll: 32 x dwordx4 sc1 until each 64b half shows epoch==s ----
    u32x4 g[32];
    while (true) {
#define GLD(I, OFS) asm volatile("global_load_dwordx4 %0, %1, %2 offset:" OFS " sc1" \
                                 : "=v"(g[I]) : "v"(rd_voff), "s"(hxbase) : "memory")
      GLD(0,"0");    GLD(1,"16");   GLD(2,"128");  GLD(3,"144");
      GLD(4,"256");  GLD(5,"272");  GLD(6,"384");  GLD(7,"400");
      GLD(8,"512");  GLD(9,"528");  GLD(10,"640"); GLD(11,"656");
      GLD(12,"768"); GLD(13,"784"); GLD(14,"896"); GLD(15,"912");
      GLD(16,"1024");GLD(17,"1040");GLD(18,"1152");GLD(19,"1168");
      GLD(20,"1280");GLD(21,"1296");GLD(22,"1408");GLD(23,"1424");
      GLD(24,"1536");GLD(25,"1552");GLD(26,"1664");GLD(27,"1680");
      GLD(28,"1792");GLD(29,"1808");GLD(30,"1920");GLD(31,"1936");
#undef GLD
      asm volatile("s_waitcnt vmcnt(0)" ::: "memory");
      __builtin_amdgcn_sched_barrier(0);
      bool ok = staleok;
      if (!ok) {
        ok = true;
        #pragma unroll
        for (int i = 0; i < 32; ++i)
          ok = ok && (g[i].y == tgt) && (g[i].w == tgt);
      }
      if (__all(ok)) break;
      __builtin_amdgcn_s_sleep(1);
    }
    __builtin_amdgcn_sched_barrier(0);
    unsigned int x0 = nx0, x1 = nx1, x2 = nx2, x3 = nx3;  // xg drained by vmcnt(0)

    // ---- 2. MFMA: assemble A-frags (data at .x/.z), B from LDS, split chains ----
    f32x4 a0e = {0.f,0.f,0.f,0.f}, a0o = {0.f,0.f,0.f,0.f};
    f32x4 a1e = {0.f,0.f,0.f,0.f}, a1o = {0.f,0.f,0.f,0.f};
    #pragma unroll
    for (int kt = 0; kt < 16; kt += 2) {
      u32x4 t0v = { g[2*kt].x,   g[2*kt].z,   g[2*kt+1].x, g[2*kt+1].z };
      u32x4 t1v = { g[2*kt+2].x, g[2*kt+2].z, g[2*kt+3].x, g[2*kt+3].z };
      f16x8 aE = __builtin_bit_cast(f16x8, t0v);
      f16x8 aO = __builtin_bit_cast(f16x8, t1v);
      int sl0 = kt*4 + half, sl1 = (kt+1)*4 + half;
      f16x8 b0a = *(const f16x8*)((const char*)Wl + r0f*1024 + ((sl0 ^ (r0f & 7)) << 4));
      f16x8 b1a = *(const f16x8*)((const char*)Wl + r1f*1024 + ((sl0 ^ (r1f & 7)) << 4));
      f16x8 b0b = *(const f16x8*)((const char*)Wl + r0f*1024 + ((sl1 ^ (r0f & 7)) << 4));
      f16x8 b1b = *(const f16x8*)((const char*)Wl + r1f*1024 + ((sl1 ^ (r1f & 7)) << 4));
      a0e = __builtin_amdgcn_mfma_f32_16x16x32_f16(aE, b0a, a0e, 0, 0, 0);
      a1e = __builtin_amdgcn_mfma_f32_16x16x32_f16(aE, b1a, a1e, 0, 0, 0);
      a0o = __builtin_amdgcn_mfma_f32_16x16x32_f16(aO, b0b, a0o, 0, 0, 0);
      a1o = __builtin_amdgcn_mfma_f32_16x16x32_f16(aO, b1b, a1o, 0, 0, 0);
    }
    f32x4 acc0 = a0e + a0o;
    f32x4 acc1 = a1e + a1o;

    // ---- 3. gs transpose (same-wave produce/consume) ----
    #pragma unroll
    for (int j = 0; j < 4; ++j) {
      int srow = wv*16 + (lane >> 4)*4 + j;
      gs[srow*33 + (lane & 15)]      = acc0[j];
      gs[srow*33 + 16 + (lane & 15)] = acc1[j];
    }

    // ---- 4. gates ----
    {
      f16x2 p0 = __builtin_bit_cast(f16x2, x0);
      f16x2 p1 = __builtin_bit_cast(f16x2, x1);
      f16x2 p2 = __builtin_bit_cast(f16x2, x2);
      f16x2 p3 = __builtin_bit_cast(f16x2, x3);
      const int q = myseq*33;
      float vi0 = gs[q + hcA]         + (float)p0[0];
      float vi1 = gs[q + hcA + 1]     + (float)p0[1];
      float vf0 = gs[q + 8 + hcA]     + (float)p1[0];
      float vf1 = gs[q + 8 + hcA + 1] + (float)p1[1];
      float vg0 = gs[q + 16 + hcA]    + (float)p2[0];
      float vg1 = gs[q + 16 + hcA+1]  + (float)p2[1];
      float vo0 = gs[q + 24 + hcA]    + (float)p3[0];
      float vo1 = gs[q + 24 + hcA+1]  + (float)p3[1];
      if (act) {
        float i0 = sigf(vi0), f0 = sigf(vf0), G0 = tanh_(vg0), o0 = sigf(vo0);
        float i1 = sigf(vi1), f1 = sigf(vf1), G1 = tanh_(vg1), o1 = sigf(vo1);
        c0 = f0*c0 + i0*G0;
        c1 = f1*c1 + i1*G1;
        h0k = o0*tanh_(c0);
        h1k = o1*tanh_(c1);
        hold = (unsigned int)f2h(h0k) | ((unsigned int)f2h(h1k) << 16);
      }
    }

    // ---- 5. granule store {cols01, ep, cols23, ep}, NO ack wait ----
    unsigned int hp = __shfl_xor(hold, 1);     // partner's 2 cols (all lanes exec)
    if (is_writer && act) {
      u32x4 st = { hold, (unsigned int)(s + 1), hp, (unsigned int)(s + 1) };
      asm volatile("global_store_dwordx4 %0, %1, %2 sc1"
                   :: "v"(wr_voff), "v"(st), "s"(hxbase) : "memory");
    }
    // out1 (plain cached)
    if (LAYER == 0) {
      if (act) {
        int pos = dir ? (mylen - 1 - s) : s;
        *(unsigned int*)(g_out1 + ((size_t)myseq*T_ + pos)*1024 + dir*H_ + col0 + hcA) = hold;
      }
    }

    // ---- 6. xg(s+1) prefetch (drained by next poll's vmcnt(0)) ----
    {
      int s1 = s + 1;
      int p1 = dir ? (mylen - 1 - s1) : s1;
      p1 = p1 < 0 ? 0 : (p1 > mylen - 1 ? mylen - 1 : p1);
      const char* xr = xbase + (size_t)p1*4096;
      asm volatile("global_load_dword %0, %1, off"             : "=v"(nx0) : "v"(xr) : "memory");
      asm volatile("global_load_dword %0, %1, off offset:1024" : "=v"(nx1) : "v"(xr) : "memory");
      asm volatile("global_load_dword %0, %1, off offset:2048" : "=v"(nx2) : "v"(xr) : "memory");
      asm volatile("global_load_dword %0, %1, off offset:3072" : "=v"(nx3) : "v"(xr) : "memory");
    }

    rb = wb;
  }

  // ---- LAYER 1: final h written once ----
  if (LAYER == 1) {
    g_hlast[dir][myseq*H_ + col0 + hcA]     = h0k;
    g_hlast[dir][myseq*H_ + col0 + hcA + 1] = h1k;
  }
}

// ---------------- final projection ----------------
__global__ void k_final(const float* __restrict__ w_out, const float* __restrict__ b_out,
                        float* __restrict__ out) {
  const int b = blockIdx.x;
  const int tid = threadIdx.x;
  float sum = 0.f;
  for (int k = tid; k < 1024; k += 256) {
    float h = (k < 512) ? g_hlast[0][b*H_ + k] : g_hlast[1][b*H_ + k - 512];
    sum += h * w_out[k];
  }
  __shared__ float red[256];
  red[tid] = sum;
  __syncthreads();
  for (int st = 128; st > 0; st >>= 1) {
    if (tid < st) red[tid] += red[tid + st];
    __syncthreads();
  }
  if (tid == 0) out[b] = 1.f/(1.f + __expf(-(red[0] + b_out[0])));
}

// ---------------- launch ----------------
extern "C" void kernel_launch(void* const* d_in, const int* in_sizes, int n_in,
                              void* d_out, int out_size, void* d_ws, size_t ws_size,
                              hipStream_t stream) {
  (void)in_sizes; (void)n_in; (void)d_ws; (void)ws_size; (void)out_size;
  const float* seqs    = (const float*)d_in[0];
  const int*   lens    = (const int*)d_in[1];
  const float* w_ih_l0 = (const float*)d_in[2];
  const float* w_hh_l0 = (const float*)d_in[3];
  const float* b_ih_l0 = (const float*)d_in[4];
  const float* b_hh_l0 = (const float*)d_in[5];
  const float* w_ih_l1 = (const float*)d_in[6];
  const float* w_hh_l1 = (const float*)d_in[7];
  const float* b_ih_l1 = (const float*)d_in[8];
  const float* b_hh_l1 = (const float*)d_in[9];
  const float* w_out   = (const float*)d_in[10];
  const float* b_out   = (const float*)d_in[11];
  float* outp = (float*)d_out;

  hipLaunchKernelGGL(k_init,   dim3(256),  dim3(256), 0, stream);
  hipLaunchKernelGGL(k_cvt_x,  dim3(2048), dim3(256), 0, stream, seqs);
  hipLaunchKernelGGL(k_cvt_w1, dim3(256),  dim3(256), 0, stream, w_ih_l0);
  hipLaunchKernelGGL(k_cvt_w2, dim3(512),  dim3(256), 0, stream, w_ih_l1);

  hipLaunchKernelGGL((k_xproj<0>), dim3(BT_/128, 16, 2), dim3(256), 0, stream,
                     b_ih_l0, b_hh_l0, lens);
  {
    void* args[] = { (void*)&w_hh_l0, (void*)&lens };
    hipError_t e = hipLaunchCooperativeKernel(k_scan<0>, dim3(128), dim3(256), args, 0u, stream);
    (void)e;
  }
  hipLaunchKernelGGL((k_xproj<1>), dim3(BT_/128, 16, 2), dim3(256), 0, stream,
                     b_ih_l1, b_hh_l1, lens);
  {
    void* args[] = { (void*)&w_hh_l1, (void*)&lens };
    hipError_t e = hipLaunchCooperativeKernel(k_scan<1>, dim3(128), dim3(256), args, 0u, stream);
    (void)e;
  }
  hipLaunchKernelGGL(k_final, dim3(64), dim3(256), 0, stream, w_out, b_out, outp);
}

// Round 20
// 16420.255 us; speedup vs baseline: 1.6905x; 1.6905x over previous
//
#include <hip/hip_runtime.h>
#include <stdint.h>
#include <stddef.h>

#define B_  64
#define T_  2048
#define XD  256
#define H_  512
#define G4  2048          // 4*H
#define BT_ (B_*T_)       // 131072

typedef __attribute__((ext_vector_type(8))) _Float16 f16x8;
typedef __attribute__((ext_vector_type(4))) float f32x4;
typedef __attribute__((ext_vector_type(4))) unsigned int u32x4;
typedef __attribute__((ext_vector_type(4))) unsigned short us4;
typedef __attribute__((ext_vector_type(2))) _Float16 f16x2;

// ---------------- static device scratch (total ~1.42 GB < 2 GiB PC32-reloc budget) ----
__device__ __attribute__((aligned(256))) unsigned short g_xh[(size_t)BT_*XD];         // x fp16
__device__ __attribute__((aligned(256))) unsigned short g_w1h[(size_t)2*G4*XD];       // w_ih_l0 fp16
__device__ __attribute__((aligned(256))) unsigned short g_w2h[(size_t)2*G4*1024];     // w_ih_l1 fp16
__device__ __attribute__((aligned(256))) _Float16       g_xproj[(size_t)2*BT_*G4];    // 1.07 GB fp16
__device__ __attribute__((aligned(256))) unsigned short g_out1[(size_t)BT_*1024];     // 268 MB fp16
__device__ __attribute__((aligned(256))) unsigned short g_hbuf[2][2][2][B_*H_];       // [layer][dir][pp] fp16
__device__ __attribute__((aligned(256))) float          g_hlast[2][B_*H_];            // layer2 final h
// fanout flags: [layer][dir][reader wg][writer wg] -> reader's 64 dwords contiguous (256B)
__device__ __attribute__((aligned(256))) unsigned int   g_flag[2][2][64][64];

__device__ inline unsigned short f2h(float f) {
  _Float16 h = (_Float16)f;
  return __builtin_bit_cast(unsigned short, h);
}
__device__ inline float sigf(float x)  { return 1.f/(1.f + __expf(-x)); }
__device__ inline float tanh_(float x) { return 1.f - 2.f/(__expf(2.f*x) + 1.f); }

// ---------------- merged prologue: init flags/hbuf + all fp32->fp16 converts --------
__global__ void k_prep(const float* __restrict__ xsrc,
                       const float* __restrict__ w1src,
                       const float* __restrict__ w2src) {
  const size_t tid0   = (size_t)blockIdx.x*blockDim.x + threadIdx.x;
  const size_t stride = (size_t)gridDim.x*blockDim.x;

  // zero h buffers + flags
  {
    unsigned int* hb = (unsigned int*)&g_hbuf[0][0][0][0];
    for (size_t j = tid0; j < sizeof(g_hbuf)/4; j += stride) hb[j] = 0u;
    unsigned int* fl = (unsigned int*)&g_flag[0][0][0][0];
    for (size_t j = tid0; j < sizeof(g_flag)/4; j += stride) fl[j] = 0u;
  }
  // x convert
  {
    const size_t n4 = (size_t)BT_*XD/4;
    for (size_t j = tid0; j < n4; j += stride) {
      float4 v = ((const float4*)xsrc)[j];
      us4 o = { f2h(v.x), f2h(v.y), f2h(v.z), f2h(v.w) };
      ((us4*)g_xh)[j] = o;
    }
  }
  // w_ih_l0 convert
  {
    const size_t n4 = (size_t)2*G4*XD/4;
    for (size_t j = tid0; j < n4; j += stride) {
      float4 v = ((const float4*)w1src)[j];
      us4 o = { f2h(v.x), f2h(v.y), f2h(v.z), f2h(v.w) };
      ((us4*)g_w1h)[j] = o;
    }
  }
  // w_ih_l1 convert
  {
    const size_t n4 = (size_t)2*G4*1024/4;
    for (size_t j = tid0; j < n4; j += stride) {
      float4 v = ((const float4*)w2src)[j];
      us4 o = { f2h(v.x), f2h(v.y), f2h(v.z), f2h(v.w) };
      ((us4*)g_w2h)[j] = o;
    }
  }
}

// ---------------- x_proj GEMM (r14: reg-staged, XOR-swizzled LDS) ----------------
template<int LAYER>
__global__ __launch_bounds__(256) void k_xproj(const float* __restrict__ b_ih,
                                               const float* __restrict__ b_hh,
                                               const int* __restrict__ lens) {
  constexpr int K = (LAYER == 0) ? XD : 1024;
  const unsigned short* __restrict__ Abf = (LAYER == 0) ? g_xh : g_out1;
  const unsigned short* __restrict__ Wbf = (LAYER == 0) ? g_w1h : g_w2h;

  const int m0 = blockIdx.x*128;
  const int n0 = blockIdx.y*128;
  const int d  = blockIdx.z;
  const int bseq = m0 / T_;
  const int t0   = m0 % T_;
  if (t0 >= lens[bseq]) return;

  __shared__ unsigned short As[128*64];
  __shared__ unsigned short Bs[128*64];

  const int tid  = threadIdx.x;
  const int lane = tid & 63;
  const int wv   = tid >> 6;
  const int moff = (wv >> 1)*64;
  const int noff = (wv & 1)*64;

  f32x4 acc[4][4] = {};

  const unsigned short* Ag = Abf + (size_t)m0*K;
  const unsigned short* Wg = Wbf + ((size_t)d*G4 + n0)*K;

  for (int k0 = 0; k0 < K; k0 += 64) {
    __syncthreads();
    #pragma unroll
    for (int p = 0; p < 4; ++p) {
      int sidx = p*256 + tid;
      int row = sidx >> 3;
      int ch  = sidx & 7;
      u32x4 va = *(const u32x4*)(Ag + (size_t)row*K + k0 + ch*8);
      u32x4 vb = *(const u32x4*)(Wg + (size_t)row*K + k0 + ch*8);
      int wb = row*128 + ((ch ^ (row & 7)) << 4);
      *(u32x4*)((char*)As + wb) = va;
      *(u32x4*)((char*)Bs + wb) = vb;
    }
    __syncthreads();
    #pragma unroll
    for (int kt = 0; kt < 2; ++kt) {
      int slot = kt*4 + (lane >> 4);
      f16x8 af[4], bfv[4];
      #pragma unroll
      for (int mt = 0; mt < 4; ++mt) {
        int r = moff + mt*16 + (lane & 15);
        af[mt] = *(const f16x8*)((const char*)As + r*128 + ((slot ^ (r & 7)) << 4));
      }
      #pragma unroll
      for (int nt = 0; nt < 4; ++nt) {
        int r = noff + nt*16 + (lane & 15);
        bfv[nt] = *(const f16x8*)((const char*)Bs + r*128 + ((slot ^ (r & 7)) << 4));
      }
      #pragma unroll
      for (int mt = 0; mt < 4; ++mt)
        #pragma unroll
        for (int nt = 0; nt < 4; ++nt)
          acc[mt][nt] = __builtin_amdgcn_mfma_f32_16x16x32_f16(af[mt], bfv[nt], acc[mt][nt], 0, 0, 0);
    }
  }

  #pragma unroll
  for (int nt = 0; nt < 4; ++nt) {
    const int col = n0 + noff + nt*16 + (lane & 15);
    const float bias = b_ih[d*G4 + col] + b_hh[d*G4 + col];
    #pragma unroll
    for (int mt = 0; mt < 4; ++mt) {
      const int row = m0 + moff + mt*16 + (lane >> 4)*4;
      _Float16* op = g_xproj + ((size_t)d*BT_ + row)*G4 + col;
      #pragma unroll
      for (int j = 0; j < 4; ++j)
        op[(size_t)j*G4] = (_Float16)(acc[mt][nt][j] + bias);
    }
  }
}

// ---------------- recurrent scan (r14 verbatim — banked best) ----------------
template<int LAYER>
__global__ __launch_bounds__(256, 1) void k_scan(const float* __restrict__ w_hh,
                                                 const int* __restrict__ lens) {
  const int dir  = blockIdx.x & 1;
  const int wg   = blockIdx.x >> 1;
  const int tid  = threadIdx.x;
  const int lane = tid & 63;
  const int wv   = tid >> 6;

  __shared__ unsigned short Wl[32*512];   // 32 KB, XOR-swizzled
  __shared__ float gs[64*33];             // gate scratch

  for (int i = tid; i < 32*256; i += 256) {
    int e = i*2;
    int row = e >> 9;
    int k   = e & 511;
    int gate = row >> 3, hc = row & 7;
    int grow = gate*H_ + wg*8 + hc;
    const float* wsrc = w_hh + ((size_t)dir*G4 + grow)*H_ + k;
    unsigned int pk = (unsigned int)f2h(wsrc[0]) | ((unsigned int)f2h(wsrc[1]) << 16);
    int byte = row*1024 + ((((k*2) >> 4) ^ (row & 7)) << 4) + ((k*2) & 15);
    *(unsigned int*)((char*)Wl + byte) = pk;
  }
  __syncthreads();

  const int myseq = tid >> 2;
  const int hcA   = (tid & 3)*2;
  const int mylen = lens[myseq];
  const int maxlen = lens[0];
  const int ml16  = __builtin_amdgcn_readfirstlane(lens[wv << 4]); // wave max len (SGPR)
  const int col0  = wg*8;
  const int arow  = wv*16 + (lane & 15);
  const int r0f   = lane & 15, r1f = 16 + (lane & 15);
  float c0 = 0.f, c1 = 0.f, h0k = 0.f, h1k = 0.f;
  unsigned int hold = 0u;

  unsigned short* hbuf0 = &g_hbuf[LAYER][dir][0][0];
  unsigned short* hbuf1 = &g_hbuf[LAYER][dir][1][0];
  unsigned int*   flags = &g_flag[LAYER][dir][0][0];

  const unsigned int h_voff   = (unsigned int)(arow*1024 + ((lane >> 4)*16));
  const unsigned int st_voff  = (unsigned int)((myseq*H_ + col0 + hcA)*2);
  const unsigned int fan_voff = (unsigned int)(lane*256 + wg*4);   // writer: per-reader slot
  const unsigned int pol_voff = (unsigned int)(wg*256 + lane*4);   // reader: own block

  const char* xbase = (const char*)((const unsigned int*)
      (g_xproj + (((size_t)dir*B_ + myseq)*T_)*G4 + col0) + (hcA >> 1));

  // prologue: prefetch xg for s=0 into nx*
  unsigned int nx0, nx1, nx2, nx3;
  {
    int p0 = dir ? (mylen - 1) : 0;
    const char* xr = xbase + (size_t)p0*4096;
    asm volatile("global_load_dword %0, %1, off"             : "=v"(nx0) : "v"(xr) : "memory");
    asm volatile("global_load_dword %0, %1, off offset:1024" : "=v"(nx1) : "v"(xr) : "memory");
    asm volatile("global_load_dword %0, %1, off offset:2048" : "=v"(nx2) : "v"(xr) : "memory");
    asm volatile("global_load_dword %0, %1, off offset:3072" : "=v"(nx3) : "v"(xr) : "memory");
  }

  for (int s = 0; s < maxlen; ++s) {
    const unsigned short* hread = (s & 1) ? hbuf1 : hbuf0;
    unsigned short* hwrite      = (s & 1) ? hbuf0 : hbuf1;

    if (s < ml16) {   // scalar branch: whole wave skips when its 16 seqs are done
      const bool act = s < mylen;

      // ---- 1. batched agent-scope h-load: 16 x dwordx4 sc1 ----
      f16x8 aa[16];
#define HLD(I, OFS) asm volatile("global_load_dwordx4 %0, %1, %2 offset:" OFS " sc1" \
                                 : "=v"(aa[I]) : "v"(h_voff), "s"(hread) : "memory")
      HLD(0,"0");   HLD(1,"64");  HLD(2,"128"); HLD(3,"192");
      HLD(4,"256"); HLD(5,"320"); HLD(6,"384"); HLD(7,"448");
      HLD(8,"512"); HLD(9,"576"); HLD(10,"640"); HLD(11,"704");
      HLD(12,"768"); HLD(13,"832"); HLD(14,"896"); HLD(15,"960");
#undef HLD

      // ---- 2. W-fragment ds_reads in the h-load shadow ----
      f16x8 b0r[16], b1r[16];
      #pragma unroll
      for (int kt = 0; kt < 16; ++kt) {
        int slot = kt*4 + (lane >> 4);
        b0r[kt] = *(const f16x8*)((const char*)Wl + r0f*1024 + ((slot ^ (r0f & 7)) << 4));
        b1r[kt] = *(const f16x8*)((const char*)Wl + r1f*1024 + ((slot ^ (r1f & 7)) << 4));
      }

      // ---- 3. staged consumption: MFMA groups start as granules arrive ----
      f32x4 a0e = {0.f,0.f,0.f,0.f}, a0o = {0.f,0.f,0.f,0.f};
      f32x4 a1e = {0.f,0.f,0.f,0.f}, a1o = {0.f,0.f,0.f,0.f};

      asm volatile("s_waitcnt vmcnt(12)" ::: "memory");   // prev stores+xg + aa[0..3]
      __builtin_amdgcn_sched_barrier(0);
      unsigned int x0 = nx0, x1 = nx1, x2 = nx2, x3 = nx3;
      #pragma unroll
      for (int kt = 0; kt < 4; kt += 2) {
        a0e = __builtin_amdgcn_mfma_f32_16x16x32_f16(aa[kt],   b0r[kt],   a0e, 0, 0, 0);
        a1e = __builtin_amdgcn_mfma_f32_16x16x32_f16(aa[kt],   b1r[kt],   a1e, 0, 0, 0);
        a0o = __builtin_amdgcn_mfma_f32_16x16x32_f16(aa[kt+1], b0r[kt+1], a0o, 0, 0, 0);
        a1o = __builtin_amdgcn_mfma_f32_16x16x32_f16(aa[kt+1], b1r[kt+1], a1o, 0, 0, 0);
      }
      asm volatile("s_waitcnt vmcnt(8)" ::: "memory");
      __builtin_amdgcn_sched_barrier(0);
      #pragma unroll
      for (int kt = 4; kt < 8; kt += 2) {
        a0e = __builtin_amdgcn_mfma_f32_16x16x32_f16(aa[kt],   b0r[kt],   a0e, 0, 0, 0);
        a1e = __builtin_amdgcn_mfma_f32_16x16x32_f16(aa[kt],   b1r[kt],   a1e, 0, 0, 0);
        a0o = __builtin_amdgcn_mfma_f32_16x16x32_f16(aa[kt+1], b0r[kt+1], a0o, 0, 0, 0);
        a1o = __builtin_amdgcn_mfma_f32_16x16x32_f16(aa[kt+1], b1r[kt+1], a1o, 0, 0, 0);
      }
      asm volatile("s_waitcnt vmcnt(4)" ::: "memory");
      __builtin_amdgcn_sched_barrier(0);
      #pragma unroll
      for (int kt = 8; kt < 12; kt += 2) {
        a0e = __builtin_amdgcn_mfma_f32_16x16x32_f16(aa[kt],   b0r[kt],   a0e, 0, 0, 0);
        a1e = __builtin_amdgcn_mfma_f32_16x16x32_f16(aa[kt],   b1r[kt],   a1e, 0, 0, 0);
        a0o = __builtin_amdgcn_mfma_f32_16x16x32_f16(aa[kt+1], b0r[kt+1], a0o, 0, 0, 0);
        a1o = __builtin_amdgcn_mfma_f32_16x16x32_f16(aa[kt+1], b1r[kt+1], a1o, 0, 0, 0);
      }
      asm volatile("s_waitcnt vmcnt(0)" ::: "memory");
      __builtin_amdgcn_sched_barrier(0);
      #pragma unroll
      for (int kt = 12; kt < 16; kt += 2) {
        a0e = __builtin_amdgcn_mfma_f32_16x16x32_f16(aa[kt],   b0r[kt],   a0e, 0, 0, 0);
        a1e = __builtin_amdgcn_mfma_f32_16x16x32_f16(aa[kt],   b1r[kt],   a1e, 0, 0, 0);
        a0o = __builtin_amdgcn_mfma_f32_16x16x32_f16(aa[kt+1], b0r[kt+1], a0o, 0, 0, 0);
        a1o = __builtin_amdgcn_mfma_f32_16x16x32_f16(aa[kt+1], b1r[kt+1], a1o, 0, 0, 0);
      }
      f32x4 acc0 = a0e + a0o;
      f32x4 acc1 = a1e + a1o;

      // ---- gs transpose (same-wave produce/consume) ----
      #pragma unroll
      for (int j = 0; j < 4; ++j) {
        int srow = wv*16 + (lane >> 4)*4 + j;
        gs[srow*33 + (lane & 15)]      = acc0[j];
        gs[srow*33 + 16 + (lane & 15)] = acc1[j];
      }

      // ---- gates ----
      {
        f16x2 p0 = __builtin_bit_cast(f16x2, x0);
        f16x2 p1 = __builtin_bit_cast(f16x2, x1);
        f16x2 p2 = __builtin_bit_cast(f16x2, x2);
        f16x2 p3 = __builtin_bit_cast(f16x2, x3);
        const int q = myseq*33;
        float vi0 = gs[q + hcA]         + (float)p0[0];
        float vi1 = gs[q + hcA + 1]     + (float)p0[1];
        float vf0 = gs[q + 8 + hcA]     + (float)p1[0];
        float vf1 = gs[q + 8 + hcA + 1] + (float)p1[1];
        float vg0 = gs[q + 16 + hcA]    + (float)p2[0];
        float vg1 = gs[q + 16 + hcA+1]  + (float)p2[1];
        float vo0 = gs[q + 24 + hcA]    + (float)p3[0];
        float vo1 = gs[q + 24 + hcA+1]  + (float)p3[1];
        if (act) {
          float i0 = sigf(vi0), f0 = sigf(vf0), G0 = tanh_(vg0), o0 = sigf(vo0);
          float i1 = sigf(vi1), f1 = sigf(vf1), G1 = tanh_(vg1), o1 = sigf(vo1);
          c0 = f0*c0 + i0*G0;
          c1 = f1*c1 + i1*G1;
          h0k = o0*tanh_(c0);
          h1k = o1*tanh_(c1);
          hold = (unsigned int)f2h(h0k) | ((unsigned int)f2h(h1k) << 16);
        }
      }

      // ---- stores: h-store FIRST (sc1), then out1 (LAYER0), then prefetch ----
      if (s <= mylen) {
        asm volatile("global_store_dword %0, %1, %2 sc1"
                     :: "v"(st_voff), "v"(hold), "s"(hwrite) : "memory");
      }
      if (LAYER == 0) {
        if (s < mylen) {
          int pos = dir ? (mylen - 1 - s) : s;
          *(unsigned int*)(g_out1 + ((size_t)myseq*T_ + pos)*1024 + dir*H_ + col0 + hcA) = hold;
        }
      }

      // ---- xg(s+1) prefetch (rides across the barrier) ----
      {
        int s1 = s + 1;
        int p1 = dir ? (mylen - 1 - s1) : s1;
        p1 = p1 < 0 ? 0 : (p1 > mylen - 1 ? mylen - 1 : p1);
        const char* xr = xbase + (size_t)p1*4096;
        asm volatile("global_load_dword %0, %1, off"             : "=v"(nx0) : "v"(xr) : "memory");
        asm volatile("global_load_dword %0, %1, off offset:1024" : "=v"(nx1) : "v"(xr) : "memory");
        asm volatile("global_load_dword %0, %1, off offset:2048" : "=v"(nx2) : "v"(xr) : "memory");
        asm volatile("global_load_dword %0, %1, off offset:3072" : "=v"(nx3) : "v"(xr) : "memory");
      }

      // ---- drain ONLY the sc1 h-store (oldest); out1 + prefetches keep flying ----
      if (LAYER == 0) asm volatile("s_waitcnt vmcnt(5)" ::: "memory");
      else            asm volatile("s_waitcnt vmcnt(4)" ::: "memory");
    }

    // ---- rendezvous + fanout signal + reader-local poll ----
    asm volatile("s_barrier" ::: "memory");
    if (wv == 0) {
      unsigned int fv = (unsigned int)(s + 1);
      asm volatile("global_store_dword %0, %1, %2 sc1"
                   :: "v"(fan_voff), "v"(fv), "s"(flags) : "memory");
      const unsigned int tgt = fv;
      while (true) {
        unsigned int v;
        asm volatile("global_load_dword %0, %1, %2 sc1"
                     : "=v"(v) : "v"(pol_voff), "s"(flags) : "memory");
        asm volatile("s_waitcnt vmcnt(0)" ::: "memory");
        if (__all(v >= tgt)) break;
        __builtin_amdgcn_s_sleep(1);
      }
    }
    asm volatile("s_barrier" ::: "memory");
  }

  // ---- LAYER 1: final h written once ----
  if (LAYER == 1) {
    g_hlast[dir][myseq*H_ + col0 + hcA]     = h0k;
    g_hlast[dir][myseq*H_ + col0 + hcA + 1] = h1k;
  }
}

// ---------------- final projection ----------------
__global__ void k_final(const float* __restrict__ w_out, const float* __restrict__ b_out,
                        float* __restrict__ out) {
  const int b = blockIdx.x;
  const int tid = threadIdx.x;
  float sum = 0.f;
  for (int k = tid; k < 1024; k += 256) {
    float h = (k < 512) ? g_hlast[0][b*H_ + k] : g_hlast[1][b*H_ + k - 512];
    sum += h * w_out[k];
  }
  __shared__ float red[256];
  red[tid] = sum;
  __syncthreads();
  for (int st = 128; st > 0; st >>= 1) {
    if (tid < st) red[tid] += red[tid + st];
    __syncthreads();
  }
  if (tid == 0) out[b] = 1.f/(1.f + __expf(-(red[0] + b_out[0])));
}

// ---------------- launch ----------------
extern "C" void kernel_launch(void* const* d_in, const int* in_sizes, int n_in,
                              void* d_out, int out_size, void* d_ws, size_t ws_size,
                              hipStream_t stream) {
  (void)in_sizes; (void)n_in; (void)d_ws; (void)ws_size; (void)out_size;
  const float* seqs    = (const float*)d_in[0];
  const int*   lens    = (const int*)d_in[1];
  const float* w_ih_l0 = (const float*)d_in[2];
  const float* w_hh_l0 = (const float*)d_in[3];
  const float* b_ih_l0 = (const float*)d_in[4];
  const float* b_hh_l0 = (const float*)d_in[5];
  const float* w_ih_l1 = (const float*)d_in[6];
  const float* w_hh_l1 = (const float*)d_in[7];
  const float* b_ih_l1 = (const float*)d_in[8];
  const float* b_hh_l1 = (const float*)d_in[9];
  const float* w_out   = (const float*)d_in[10];
  const float* b_out   = (const float*)d_in[11];
  float* outp = (float*)d_out;

  hipLaunchKernelGGL(k_prep, dim3(2048), dim3(256), 0, stream, seqs, w_ih_l0, w_ih_l1);

  hipLaunchKernelGGL((k_xproj<0>), dim3(BT_/128, 16, 2), dim3(256), 0, stream,
                     b_ih_l0, b_hh_l0, lens);
  {
    void* args[] = { (void*)&w_hh_l0, (void*)&lens };
    hipError_t e = hipLaunchCooperativeKernel(k_scan<0>, dim3(128), dim3(256), args, 0u, stream);
    (void)e;
  }
  hipLaunchKernelGGL((k_xproj<1>), dim3(BT_/128, 16, 2), dim3(256), 0, stream,
                     b_ih_l1, b_hh_l1, lens);
  {
    void* args[] = { (void*)&w_hh_l1, (void*)&lens };
    hipError_t e = hipLaunchCooperativeKernel(k_scan<1>, dim3(128), dim3(256), args, 0u, stream);
    (void)e;
  }
  hipLaunchKernelGGL(k_final, dim3(64), dim3(256), 0, stream, w_out, b_out, outp);
}